// Round 3
// baseline (326.151 us; speedup 1.0000x reference)
//
#include <hip/hip_runtime.h>

typedef float f32x4 __attribute__((ext_vector_type(4)));
typedef _Float16 f16x8 __attribute__((ext_vector_type(8)));
typedef _Float16 f16x2 __attribute__((ext_vector_type(2)));

#define NB 256
#define NL 256
#define NIN 256
#define ND 128
#define NH 64
#define CH 16                        // X-chunk (steps)

// raw barrier: LDS-only drain — global ops float across it
#define BAR_LDS() asm volatile("s_waitcnt lgkmcnt(0)\n\ts_barrier" ::: "memory")

// =====================================================================
// Kernel W: pack w_r|w_z|w_h (f32 [128][256]) into f16 fragment order.
// wpk[((nt*8+kc)*64+lane)*8+j] = w_gate[(nt&7)*16+(lane&15)]
//                                 [kc*32+(lane>>4)*8+j];  192 KB, L2-hot.
// =====================================================================
__global__ void kwpack_kernel(const float* __restrict__ w_r,
                              const float* __restrict__ w_z,
                              const float* __restrict__ w_h,
                              _Float16* __restrict__ wpk) {
  const int lane = threadIdx.x;        // 0..63
  const int nt = blockIdx.x;           // 0..23
  const int kc = blockIdx.y;           // 0..7
  const float* wg = (nt < 8) ? w_r : (nt < 16) ? w_z : w_h;
  const int col = (nt & 7) * 16 + (lane & 15);
  const int k0 = kc * 32 + (lane >> 4) * 8;
  const float4* p = (const float4*)(wg + (size_t)col * NIN + k0);
  float4 v0 = p[0], v1 = p[1];
  f16x8 f;
  f[0] = (_Float16)v0.x; f[1] = (_Float16)v0.y;
  f[2] = (_Float16)v0.z; f[3] = (_Float16)v0.w;
  f[4] = (_Float16)v1.x; f[5] = (_Float16)v1.y;
  f[6] = (_Float16)v1.z; f[7] = (_Float16)v1.w;
  *(f16x8*)&wpk[(((size_t)nt * 8 + kc) * 64 + lane) * 8] = f;
}

// =====================================================================
// Kernel C v10: FUSED projection + scan (kproj eliminated).
//  - 8 waves, wave w owns d in [16w, 16w+16).
//  - chunk-ahead pipeline inside the scan loop:
//      tin0: load x rows (t0n..t0n+15) f32 -> regs
//      tin4: cvt -> Axt LDS tile (padded) + a=sigmoid(x.k12) -> sA
//      tin7-10: W-frags from wpk (L2-hot) + 8 MFMA/gate -> Xl[buf^1]
//  - accL/accH split: a is block-uniform per step, so scale AFTER the
//    MFMAs in f32 (owner lanes) instead of f16-splat pk_mul before.
//    Removes all per-step splat/pk_mul VALU.
//  - Xl layout simplified: [buf][g][tin][d] (no permutation needed).
// =====================================================================
__global__ __launch_bounds__(512, 2) void kscan_kernel(
    const float* __restrict__ u_r, const float* __restrict__ u_z,
    const float* __restrict__ u_h, const float* __restrict__ b_r,
    const float* __restrict__ b_z, const float* __restrict__ b_h,
    const int* __restrict__ cor, const float* __restrict__ x,
    const _Float16* __restrict__ wpk, const float* __restrict__ k1k2,
    float* __restrict__ out) {
  const int b = blockIdx.x;
  const int tid = threadIdx.x;
  const int lane = tid & 63;
  const int w = tid >> 6;        // wave id 0..7 -> d range [16w, 16w+16)
  const int quad = lane >> 4;
  const int l16 = lane & 15;
  const int q8 = quad * 8;

  __shared__ __align__(16) _Float16 hist[(NL + 1) * NH];   // 32896 B
  __shared__ __align__(16) _Float16 Xl[2 * 3 * CH * ND];   // 24576 B
  __shared__ __align__(16) _Float16 Axt[16 * 264];         // 8448 B (padded)
  __shared__ __align__(16) _Float16 hprev16[2][NH];        // 256 B
  __shared__ float sA[NL];
  __shared__ int sCor[NL];
  __shared__ float k12[NIN];

  // ---- U fragments: u_g[n][k] f16; n = 16w+l16, k = kk*32+q8+j ----
  f16x8 bf[3][4];
#pragma unroll
  for (int g = 0; g < 3; ++g) {
    const float* ug = (g == 0) ? u_r : (g == 1) ? u_z : u_h;
    const float* base = ug + (size_t)(16 * w + l16) * ND;
#pragma unroll
    for (int kk = 0; kk < 4; ++kk) {
      const float4* p = (const float4*)(base + kk * 32 + q8);
      float4 v0 = p[0], v1 = p[1];
      f16x8 f;
      f[0] = (_Float16)v0.x; f[1] = (_Float16)v0.y;
      f[2] = (_Float16)v0.z; f[3] = (_Float16)v0.w;
      f[4] = (_Float16)v1.x; f[5] = (_Float16)v1.y;
      f[6] = (_Float16)v1.z; f[7] = (_Float16)v1.w;
      bf[g][kk] = f;
    }
  }

  const size_t rowb = (size_t)b * NL;
  if (tid < NH) { hprev16[0][tid] = (_Float16)0.f; hist[tid] = (_Float16)0.f; }
  if (tid < NL) {
    sCor[tid] = cor[rowb + tid];
    k12[tid] = k1k2[tid] - k1k2[NIN + tid];
  }

  // ---- chunk-GEMM thread mapping: row = tid>>5 (0..15), k8 = tid&31 ----
  const int xrow = tid >> 5;
  const int k8 = tid & 31;
  const float* xbase = x + rowb * NIN + (size_t)k8 * 8;

  const f32x4 kZ = (f32x4){0.f, 0.f, 0.f, 0.f};
  float4 xr0, xr1;           // staged x (8 f32/thread), tin0 -> tin4
  f16x8 bfr[8];              // W-frags for one gate (persist 1 step)

  auto LOADX = [&](int t0) {
    const float4* p = (const float4*)(xbase + (size_t)(t0 + xrow) * NIN);
    xr0 = p[0]; xr1 = p[1];
  };
  auto STAGEX = [&](int t0) {
    f16x8 hx;
    hx[0] = (_Float16)xr0.x; hx[1] = (_Float16)xr0.y;
    hx[2] = (_Float16)xr0.z; hx[3] = (_Float16)xr0.w;
    hx[4] = (_Float16)xr1.x; hx[5] = (_Float16)xr1.y;
    hx[6] = (_Float16)xr1.z; hx[7] = (_Float16)xr1.w;
    *(f16x8*)&Axt[xrow * 264 + k8 * 8] = hx;
    const float4* kk = (const float4*)&k12[k8 * 8];
    float4 k0 = kk[0], k1 = kk[1];
    float pd = xr0.x * k0.x + xr0.y * k0.y + xr0.z * k0.z + xr0.w * k0.w +
               xr1.x * k1.x + xr1.y * k1.y + xr1.z * k1.z + xr1.w * k1.w;
    pd += __shfl_xor(pd, 1);
    pd += __shfl_xor(pd, 2);
    pd += __shfl_xor(pd, 4);
    pd += __shfl_xor(pd, 8);
    pd += __shfl_xor(pd, 16);
    if (k8 == 0) sA[t0 + xrow] = 1.f / (1.f + __expf(-pd));
  };
  auto LOADB = [&](int g) {
    const int nt = g * 8 + w;
#pragma unroll
    for (int kk = 0; kk < 8; ++kk)
      bfr[kk] = *(const f16x8*)&wpk[(((size_t)nt * 8 + kk) * 64 + lane) * 8];
  };
  auto GEMMG = [&](int g, int nb) {
    f32x4 accP = kZ;
#pragma unroll
    for (int kk = 0; kk < 8; ++kk) {
      f16x8 af = *(const f16x8*)&Axt[l16 * 264 + kk * 32 + q8];
      accP = __builtin_amdgcn_mfma_f32_16x16x32_f16(af, bfr[kk], accP, 0, 0, 0);
    }
    _Float16* xd = &Xl[((nb * 3 + g) * CH + quad * 4) * ND + 16 * w + l16];
#pragma unroll
    for (int r = 0; r < 4; ++r) xd[r * ND] = (_Float16)accP[r];
  };

  // ---- prologue: build chunk 0 ----
  LOADX(0);
  __syncthreads();           // k12 / inits visible
  STAGEX(0);
  __syncthreads();           // Axt + sA visible
  LOADB(0); GEMMG(0, 0);
  LOADB(1); GEMMG(1, 0);
  LOADB(2); GEMMG(2, 0);
  __syncthreads();           // Xl[0] visible

  const bool owner = (quad == 0);
  const int d = 16 * w + l16;
  float bbv[3] = {0.f, 0.f, 0.f};
  if (owner) { bbv[0] = b_r[d]; bbv[1] = b_z[d]; bbv[2] = b_h[d]; }

  // ---- pipelined per-step state ----
  float a_c = sA[0];
  int c0 = sCor[0];
  int ieff_c = (c0 == 0) ? 0 : c0;
  bool pf_c = true;
  float hp = 0.f;            // own h_{t-1} (owner lanes)
  f32x4 accL[3], accH[3];
#pragma unroll
  for (int g = 0; g < 3; ++g) { accL[g] = kZ; accH[g] = kZ; }

  for (int t = 0; t < NL; ++t) {
    const int par = t & 1;
    const float a = a_c;
    const float oma = 1.f - a;
    const int ieff = ieff_c;
    const int cur = (t >> 4) & 1;
    const int tin = t & 15;
    const int t0n = (t & ~15) + 16;
    const bool prep = (t0n < NL);

    // ---- chunk-ahead projection pipeline ----
    if (prep) {
      if (tin == 0)       LOADX(t0n);
      else if (tin == 4)  STAGEX(t0n);
      else if (tin == 7)  LOADB(0);
      else if (tin == 8)  { GEMMG(0, cur ^ 1); LOADB(1); }
      else if (tin == 9)  { GEMMG(1, cur ^ 1); LOADB(2); }
      else if (tin == 10) GEMMG(2, cur ^ 1);
    }

    // ---- late-H path: hist row only became readable at this barrier ----
    if (!pf_c) {
      f16x8 g2 = *(const f16x8*)&hist[ieff * NH + q8];
      f16x8 g3 = *(const f16x8*)&hist[ieff * NH + 32 + q8];
#pragma unroll
      for (int g = 0; g < 3; ++g) {
        accH[g] = __builtin_amdgcn_mfma_f32_16x16x32_f16(g2, bf[g][2], kZ, 0, 0, 0);
        accH[g] = __builtin_amdgcn_mfma_f32_16x16x32_f16(g3, bf[g][3], accH[g], 0, 0, 0);
      }
    }

    // ---- L-half: h_{t-1} raw (no scaling — folded into epilogue) ----
    f16x8 h0 = *(const f16x8*)&hprev16[par][q8];
    f16x8 h1 = *(const f16x8*)&hprev16[par][32 + q8];
#pragma unroll
    for (int g = 0; g < 3; ++g) {
      accL[g] = __builtin_amdgcn_mfma_f32_16x16x32_f16(h0, bf[g][0], kZ, 0, 0, 0);
      accL[g] = __builtin_amdgcn_mfma_f32_16x16x32_f16(h1, bf[g][1], accL[g], 0, 0, 0);
    }

    // ---- X + md for this step (owner lanes) ----
    float xv[3], md = 0.f;
    if (owner) {
#pragma unroll
      for (int g = 0; g < 3; ++g)
        xv[g] = (float)Xl[((cur * 3 + g) * CH + tin) * ND + d];
      if (w < 4) {
        md = a * hp;
      } else if (ieff == t) {
        md = oma * hp;
      } else {
        md = oma * (float)hist[ieff * NH + (d - NH)];
      }
    }

    // ---- prefetch step-(t+1) state ----
    const int tn = (t < NL - 1) ? t + 1 : t;
    float a_n = sA[tn];
    int c_n = sCor[tn];
    int ieff_n = (c_n == 0) ? tn : c_n;
    bool pf_n = (ieff_n <= t);         // hist row readable before barrier?

    // ---- epilogue (owner lanes): combine a*L + (1-a)*H in f32 ----
    if (owner) {
      float mr = a * accL[0][0] + oma * accH[0][0];
      float mz = a * accL[1][0] + oma * accH[1][0];
      float mh = a * accL[2][0] + oma * accH[2][0];
      float er = __expf(-(xv[0] + bbv[0] + mr));
      float rr = __builtin_amdgcn_rcpf(1.f + er);
      float ez = __expf(-(xv[1] + bbv[1] + mz));
      float zz = __builtin_amdgcn_rcpf(1.f + ez);
      float e2 = __expf(2.f * (xv[2] + bbv[2] + rr * mh));
      float hh = (e2 - 1.f) * __builtin_amdgcn_rcpf(e2 + 1.f);
      float h = md + zz * (hh - md);   // (1-z)*m + z*hh
      hp = h;
      out[(rowb + t) * ND + d] = h;    // never drained per-step
      if (d < NH) hprev16[par ^ 1][d] = (_Float16)h;
      else        hist[(t + 1) * NH + (d - NH)] = (_Float16)h;
    }

    // ---- pre-issue next step's H half if its hist row is stable ----
    if (pf_n) {
      f16x8 g2 = *(const f16x8*)&hist[ieff_n * NH + q8];
      f16x8 g3 = *(const f16x8*)&hist[ieff_n * NH + 32 + q8];
#pragma unroll
      for (int g = 0; g < 3; ++g) {
        accH[g] = __builtin_amdgcn_mfma_f32_16x16x32_f16(g2, bf[g][2], kZ, 0, 0, 0);
        accH[g] = __builtin_amdgcn_mfma_f32_16x16x32_f16(g3, bf[g][3], accH[g], 0, 0, 0);
      }
    }

    BAR_LDS();

    a_c = a_n; ieff_c = ieff_n; pf_c = pf_n;
  }
}

// =====================================================================
extern "C" void kernel_launch(void* const* d_in, const int* in_sizes, int n_in,
                              void* d_out, int out_size, void* d_ws, size_t ws_size,
                              hipStream_t stream) {
  (void)in_sizes; (void)n_in; (void)out_size; (void)ws_size;
  const float* x    = (const float*)d_in[0];
  const int*   cor  = (const int*)d_in[1];
  const float* w_r  = (const float*)d_in[2];
  const float* b_r  = (const float*)d_in[3];
  const float* u_r  = (const float*)d_in[4];
  const float* w_z  = (const float*)d_in[5];
  const float* b_z  = (const float*)d_in[6];
  const float* u_z  = (const float*)d_in[7];
  const float* w_h  = (const float*)d_in[8];
  const float* b_h  = (const float*)d_in[9];
  const float* u_h  = (const float*)d_in[10];
  const float* k1k2 = (const float*)d_in[11];

  _Float16* wpk = (_Float16*)d_ws;   // 192 KB, L2-hot

  kwpack_kernel<<<dim3(24, 8), dim3(64), 0, stream>>>(w_r, w_z, w_h, wpk);
  kscan_kernel<<<dim3(NB), dim3(512), 0, stream>>>(u_r, u_z, u_h, b_r, b_z, b_h,
                                                   cor, x, wpk, k1k2,
                                                   (float*)d_out);
}

// Round 4
// 306.487 us; speedup vs baseline: 1.0642x; 1.0642x over previous
//
#include <hip/hip_runtime.h>

typedef float f32x4 __attribute__((ext_vector_type(4)));
typedef _Float16 f16x8 __attribute__((ext_vector_type(8)));
typedef _Float16 f16x2 __attribute__((ext_vector_type(2)));

#define NB 256
#define NL 256
#define NIN 256
#define ND 128
#define NH 64
#define BL (NB * NL)                 // 65536 rows
#define BLD ((size_t)BL * ND)        // 8,388,608 elements per gate
#define CH 16                        // X-staging chunk (steps)

// raw barrier: LDS-only drain (no vmcnt!) — global ops float across it
#define BAR_LDS() asm volatile("s_waitcnt lgkmcnt(0)\n\ts_barrier" ::: "memory")
#define WAIT_VM0() asm volatile("s_waitcnt vmcnt(0)" ::: "memory")

__device__ __forceinline__ void gload_lds16(const _Float16* gp, _Float16* lp) {
  __builtin_amdgcn_global_load_lds(
      (const __attribute__((address_space(1))) void*)gp,
      (__attribute__((address_space(3))) void*)lp, 16, 0, 0);
}

// =====================================================================
// Kernel W: pack w_r|w_z|w_h (f32 [128][256]) into f16 fragment order.
// =====================================================================
__global__ void kwpack_kernel(const float* __restrict__ w_r,
                              const float* __restrict__ w_z,
                              const float* __restrict__ w_h,
                              _Float16* __restrict__ wpk) {
  const int lane = threadIdx.x;        // 0..63
  const int nt = blockIdx.x;           // 0..23
  const int kc = blockIdx.y;           // 0..7
  const float* wg = (nt < 8) ? w_r : (nt < 16) ? w_z : w_h;
  const int col = (nt & 7) * 16 + (lane & 15);
  const int k0 = kc * 32 + (lane >> 4) * 8;
  const float4* p = (const float4*)(wg + (size_t)col * NIN + k0);
  float4 v0 = p[0], v1 = p[1];
  f16x8 f;
  f[0] = (_Float16)v0.x; f[1] = (_Float16)v0.y;
  f[2] = (_Float16)v0.z; f[3] = (_Float16)v0.w;
  f[4] = (_Float16)v1.x; f[5] = (_Float16)v1.y;
  f[6] = (_Float16)v1.z; f[7] = (_Float16)v1.w;
  *(f16x8*)&wpk[(((size_t)nt * 8 + kc) * 64 + lane) * 8] = f;
}

// =====================================================================
// Kernel B v6 (identical to R2's): MFMA main loop + LDS-transpose epilogue.
// Layout contract with kscan: wsX[g*BLD + row*ND + pos(d)],
//   pos(d = 32q+16s+r) = 32q + s + 2r
// =====================================================================
__global__ __launch_bounds__(256, 2) void kproj_kernel(
    const float* __restrict__ x, const _Float16* __restrict__ wpk,
    const float* __restrict__ k1k2, _Float16* __restrict__ wsX,
    float* __restrict__ wsA) {
  const int r0 = blockIdx.x * 64;

  __shared__ __align__(16) _Float16 Ah[2][64 * 40];   // 10240 B
  __shared__ float k12[NIN];                          // 1024 B
  __shared__ __align__(16) _Float16 T[64 * 392];      // 50176 B transpose buf

  const int tid = threadIdx.x;
  const int lane = tid & 63;
  const int w = tid >> 6;
  const int l16 = lane & 15;
  const int quad = lane >> 4;
  const int q8 = quad * 8;

  k12[tid] = k1k2[tid] - k1k2[NIN + tid];

  const int srow = tid >> 2;          // 0..63
  const int seg = tid & 3;            // 8-float segment within 32-float kc
  const float4* xrow4 = (const float4*)(x + (size_t)(r0 + srow) * NIN + seg * 8);

  f32x4 acc[6][4];                    // [n-tile][m-tile]
#pragma unroll
  for (int i = 0; i < 6; ++i)
#pragma unroll
    for (int mt = 0; mt < 4; ++mt) acc[i][mt] = (f32x4){0.f, 0.f, 0.f, 0.f};

  // preload kc=0: x regs + B frags
  float4 xa = xrow4[0], xb = xrow4[1];
  f16x8 bcur[6], bnxt[6];
#pragma unroll
  for (int i = 0; i < 6; ++i)
    bcur[i] = *(const f16x8*)&wpk[(((size_t)(6 * w + i) * 8 + 0) * 64 + lane) * 8];

  float adot = 0.f;
  __syncthreads();                    // k12 visible

  for (int kc = 0; kc < 8; ++kc) {
    const int buf = kc & 1;
    // ---- ka partial (fp32, pre-truncation) ----
    {
      const float4* kk = (const float4*)&k12[kc * 32 + seg * 8];
      float4 k0 = kk[0], k1 = kk[1];
      adot += xa.x * k0.x + xa.y * k0.y + xa.z * k0.z + xa.w * k0.w +
              xb.x * k1.x + xb.y * k1.y + xb.z * k1.z + xb.w * k1.w;
    }
    // ---- cvt + stage x chunk ----
    {
      f16x8 h;
      h[0] = (_Float16)xa.x; h[1] = (_Float16)xa.y;
      h[2] = (_Float16)xa.z; h[3] = (_Float16)xa.w;
      h[4] = (_Float16)xb.x; h[5] = (_Float16)xb.y;
      h[6] = (_Float16)xb.z; h[7] = (_Float16)xb.w;
      *(f16x8*)&Ah[buf][srow * 40 + seg * 8] = h;
    }
    // ---- issue next-kc loads (x + B); in flight across the barrier ----
    if (kc < 7) {
      xa = xrow4[(kc + 1) * 8];
      xb = xrow4[(kc + 1) * 8 + 1];
#pragma unroll
      for (int i = 0; i < 6; ++i)
        bnxt[i] = *(const f16x8*)&wpk[(((size_t)(6 * w + i) * 8 + (kc + 1)) * 64 + lane) * 8];
    }
    BAR_LDS();   // lgkm drain only — global loads NOT drained

    // ---- A frags + MFMA ----
    f16x8 af[4];
#pragma unroll
    for (int mt = 0; mt < 4; ++mt)
      af[mt] = *(const f16x8*)&Ah[buf][(mt * 16 + l16) * 40 + q8];
#pragma unroll
    for (int i = 0; i < 6; ++i)
#pragma unroll
      for (int mt = 0; mt < 4; ++mt)
        acc[i][mt] = __builtin_amdgcn_mfma_f32_16x16x32_f16(af[mt], bcur[i], acc[i][mt], 0, 0, 0);
#pragma unroll
    for (int i = 0; i < 6; ++i) bcur[i] = bnxt[i];
  }

  // ---- ka reduce + store (lanes tid%4==0) ----
  adot += __shfl_xor(adot, 1);
  adot += __shfl_xor(adot, 2);
  if ((tid & 3) == 0) wsA[r0 + srow] = 1.f / (1.f + __expf(-adot));

  // ---- epilogue phase 1: pair-writes into T (permutation resolved in LDS)
#pragma unroll
  for (int i = 0; i < 6; i += 2) {
    const int nt = 6 * w + i;          // even; pair never straddles a gate
    const int g = nt >> 3;
    const int q = (nt & 7) >> 1;
    _Float16* trow = T + g * 128 + q * 32 + 2 * l16;
#pragma unroll
    for (int mt = 0; mt < 4; ++mt)
#pragma unroll
      for (int r = 0; r < 4; ++r) {
        const int row = mt * 16 + quad * 4 + r;   // block-local output row
        f16x2 pr;
        pr[0] = (_Float16)acc[i][mt][r];
        pr[1] = (_Float16)acc[i + 1][mt][r];
        *(f16x2*)&trow[row * 392] = pr;
      }
  }
  __syncthreads();

  // ---- epilogue phase 2: coalesced stream-out (1KB/instr) ----
#pragma unroll
  for (int g = 0; g < 3; ++g) {
    _Float16* dstg = wsX + (size_t)g * BLD + (size_t)r0 * ND;
#pragma unroll
    for (int p = 0; p < 4; ++p) {
      const int row = 16 * w + 4 * p + quad;
      const f16x8 v = *(const f16x8*)&T[row * 392 + g * 128 + l16 * 8];
      *(f16x8*)&dstg[(size_t)row * ND + l16 * 8] = v;
    }
  }
}

// =====================================================================
// Kernel C v11: 8-wave d-split (512 threads), accL/accH f32-combine.
//  vs v9 (R2, 183.5us):
//  - NO per-step f16 splat/pk_mul pre-scaling: A-frags enter MFMA raw;
//    a / (1-a) applied in f32 in the owner epilogue (a block-uniform).
//  - MFMA dependency chains broken: accLa/accLb, accHa/accHb independent
//    (one MFMA latency off the critical path; owner sums scalars).
//  - ieff precomputed into sIeff at init (no per-step cor==0 select).
//  - everything else (8-wave split, CH staging, vmcnt at chunk edges,
//    one BAR_LDS per step, wsX permuted contract) identical to v9.
// =====================================================================
__global__ __launch_bounds__(512, 2) void kscan_kernel(
    const float* __restrict__ u_r, const float* __restrict__ u_z,
    const float* __restrict__ u_h, const float* __restrict__ b_r,
    const float* __restrict__ b_z, const float* __restrict__ b_h,
    const int* __restrict__ cor, const _Float16* __restrict__ wsX,
    const float* __restrict__ wsA, float* __restrict__ out) {
  const int b = blockIdx.x;
  const int tid = threadIdx.x;
  const int lane = tid & 63;
  const int w = tid >> 6;        // wave id 0..7 -> d range [16w, 16w+16)
  const int quad = lane >> 4;
  const int l16 = lane & 15;
  const int q8 = quad * 8;

  __shared__ __align__(16) _Float16 hist[(NL + 1) * NH];   // 32896 B
  __shared__ __align__(16) _Float16 Xl[2 * 3 * CH * ND];   // 24576 B
  __shared__ __align__(16) _Float16 hprev16[2][NH];        // 256 B (parity)
  __shared__ float sA[NL];
  __shared__ int sIeff[NL];

  // ---- U fragments: u_g[n][k] f16; n = 16w+l16, k = kk*32+q8+j ----
  f16x8 bf[3][4];
#pragma unroll
  for (int g = 0; g < 3; ++g) {
    const float* ug = (g == 0) ? u_r : (g == 1) ? u_z : u_h;
    const float* base = ug + (size_t)(16 * w + l16) * ND;
#pragma unroll
    for (int kk = 0; kk < 4; ++kk) {
      const float4* p = (const float4*)(base + kk * 32 + q8);
      float4 v0 = p[0], v1 = p[1];
      f16x8 f;
      f[0] = (_Float16)v0.x; f[1] = (_Float16)v0.y;
      f[2] = (_Float16)v0.z; f[3] = (_Float16)v0.w;
      f[4] = (_Float16)v1.x; f[5] = (_Float16)v1.y;
      f[6] = (_Float16)v1.z; f[7] = (_Float16)v1.w;
      bf[g][kk] = f;
    }
  }

  const size_t rowb = (size_t)b * NL;
  if (tid < NH) { hprev16[0][tid] = (_Float16)0.f; hist[tid] = (_Float16)0.f; }
  if (tid < NL) {
    sA[tid] = wsA[rowb + tid];
    const int c = cor[rowb + tid];
    sIeff[tid] = (c == 0) ? tid : c;
  }

  // ---- chunk 0 of X into Xl buf 0: waves 0..5, 2 per gate, 2x 1KB ----
  if (w < 6) {
    const int g = w >> 1, half = w & 1;
    const _Float16* src = wsX + (size_t)g * BLD + rowb * ND + half * 1024 + lane * 8;
    _Float16* dst = &Xl[g * (CH * ND) + half * 1024];   // wave-uniform base
    gload_lds16(src, dst);
    gload_lds16(src + 512, dst + 512);
  }

  const bool owner = (quad == 0);
  const int d = 16 * w + l16;                      // one d per owner lane
  const int xpos = 32 * (w >> 1) + (w & 1) + 2 * l16;  // permuted position
  float bbv[3] = {0.f, 0.f, 0.f};
  if (owner) { bbv[0] = b_r[d]; bbv[1] = b_z[d]; bbv[2] = b_h[d]; }
  __syncthreads();   // full drain once: chunk-0 loads + LDS init visible

  // ---- pipelined per-step state ----
  const f32x4 kZ = (f32x4){0.f, 0.f, 0.f, 0.f};
  float a_c = sA[0];
  int ieff_c = sIeff[0];               // cor[b,0] is always 0 -> ieff 0
  bool pf_c = true;
  float hp = 0.f;                      // own h_{t-1} (owner lanes)
  // t=0: hist row 0 all-zero -> H contribution 0: accs start at 0.
  f32x4 accLa[3], accLb[3], accHa[3], accHb[3];
#pragma unroll
  for (int g = 0; g < 3; ++g) {
    accLa[g] = kZ; accLb[g] = kZ; accHa[g] = kZ; accHb[g] = kZ;
  }

  for (int t = 0; t < NL; ++t) {
    const int par = t & 1;
    const float a = a_c;
    const float oma = 1.f - a;
    const int ieff = ieff_c;
    const int cur = (t >> 4) & 1;
    const int tin = t & 15;

    // ---- issue next X chunk (once per 16 steps) ----
    if (tin == 0 && t + CH < NL && w < 6) {
      const int g = w >> 1, half = w & 1;
      const _Float16* src =
          wsX + (size_t)g * BLD + (rowb + t + CH) * ND + half * 1024 + lane * 8;
      _Float16* dst = &Xl[(cur ^ 1) * (3 * CH * ND) + g * (CH * ND) + half * 1024];
      gload_lds16(src, dst);
      gload_lds16(src + 512, dst + 512);
    }

    // ---- late-H path: hist row only became readable at this barrier ----
    if (!pf_c) {
      f16x8 g2 = *(const f16x8*)&hist[ieff * NH + q8];
      f16x8 g3 = *(const f16x8*)&hist[ieff * NH + 32 + q8];
#pragma unroll
      for (int g = 0; g < 3; ++g) {
        accHa[g] = __builtin_amdgcn_mfma_f32_16x16x32_f16(g2, bf[g][2], kZ, 0, 0, 0);
        accHb[g] = __builtin_amdgcn_mfma_f32_16x16x32_f16(g3, bf[g][3], kZ, 0, 0, 0);
      }
    }

    // ---- L-half (critical): raw h_{t-1}, two INDEPENDENT MFMAs/gate ----
    f16x8 h0 = *(const f16x8*)&hprev16[par][q8];
    f16x8 h1 = *(const f16x8*)&hprev16[par][32 + q8];
#pragma unroll
    for (int g = 0; g < 3; ++g) {
      accLa[g] = __builtin_amdgcn_mfma_f32_16x16x32_f16(h0, bf[g][0], kZ, 0, 0, 0);
      accLb[g] = __builtin_amdgcn_mfma_f32_16x16x32_f16(h1, bf[g][1], kZ, 0, 0, 0);
    }

    // ---- X + md for this step (owner lanes) ----
    float xv[3], md = 0.f;
    if (owner) {
      const _Float16* xp = &Xl[cur * (3 * CH * ND) + tin * ND + xpos];
#pragma unroll
      for (int g = 0; g < 3; ++g) xv[g] = (float)xp[g * (CH * ND)];
      if (w < 4) {
        md = a * hp;
      } else if (ieff == t) {
        md = oma * hp;
      } else {
        md = oma * (float)hist[ieff * NH + (d - NH)];
      }
    }

    // ---- prefetch step-(t+1) state ----
    const int tn = (t < NL - 1) ? t + 1 : t;
    float a_n = sA[tn];
    int ieff_n = sIeff[tn];
    bool pf_n = (ieff_n <= t);         // hist row readable before barrier?

    // ---- epilogue (owner lanes): combine a*L + (1-a)*H in f32 ----
    if (owner) {
      float mr = a * (accLa[0][0] + accLb[0][0]) + oma * (accHa[0][0] + accHb[0][0]);
      float mz = a * (accLa[1][0] + accLb[1][0]) + oma * (accHa[1][0] + accHb[1][0]);
      float mh = a * (accLa[2][0] + accLb[2][0]) + oma * (accHa[2][0] + accHb[2][0]);
      float er = __expf(-(xv[0] + bbv[0] + mr));
      float rr = __builtin_amdgcn_rcpf(1.f + er);
      float ez = __expf(-(xv[1] + bbv[1] + mz));
      float zz = __builtin_amdgcn_rcpf(1.f + ez);
      float e2 = __expf(2.f * (xv[2] + bbv[2] + rr * mh));
      float hh = (e2 - 1.f) * __builtin_amdgcn_rcpf(e2 + 1.f);
      float h = md + zz * (hh - md);   // (1-z)*m + z*hh
      hp = h;
      out[(rowb + t) * ND + d] = h;    // never drained per-step
      if (d < NH) hprev16[par ^ 1][d] = (_Float16)h;
      else        hist[(t + 1) * NH + (d - NH)] = (_Float16)h;
    }

    // ---- pre-issue next step's H half if its hist row is stable ----
    if (pf_n) {
      f16x8 g2 = *(const f16x8*)&hist[ieff_n * NH + q8];
      f16x8 g3 = *(const f16x8*)&hist[ieff_n * NH + 32 + q8];
#pragma unroll
      for (int g = 0; g < 3; ++g) {
        accHa[g] = __builtin_amdgcn_mfma_f32_16x16x32_f16(g2, bf[g][2], kZ, 0, 0, 0);
        accHb[g] = __builtin_amdgcn_mfma_f32_16x16x32_f16(g3, bf[g][3], kZ, 0, 0, 0);
      }
    }

    // ---- barrier: LDS drain only; vmcnt(0) only at chunk boundaries ----
    if (tin == 15) WAIT_VM0();
    BAR_LDS();

    a_c = a_n; ieff_c = ieff_n; pf_c = pf_n;
  }
}

// =====================================================================
extern "C" void kernel_launch(void* const* d_in, const int* in_sizes, int n_in,
                              void* d_out, int out_size, void* d_ws, size_t ws_size,
                              hipStream_t stream) {
  (void)in_sizes; (void)n_in; (void)out_size; (void)ws_size;
  const float* x    = (const float*)d_in[0];
  const int*   cor  = (const int*)d_in[1];
  const float* w_r  = (const float*)d_in[2];
  const float* b_r  = (const float*)d_in[3];
  const float* u_r  = (const float*)d_in[4];
  const float* w_z  = (const float*)d_in[5];
  const float* b_z  = (const float*)d_in[6];
  const float* u_z  = (const float*)d_in[7];
  const float* w_h  = (const float*)d_in[8];
  const float* b_h  = (const float*)d_in[9];
  const float* u_h  = (const float*)d_in[10];
  const float* k1k2 = (const float*)d_in[11];

  _Float16* wsX = (_Float16*)d_ws;                                 // 48 MB
  float* wsA = (float*)((char*)d_ws + 3 * BLD * 2);                // 256 KB
  _Float16* wpk = (_Float16*)((char*)d_ws + 3 * BLD * 2 + BL * 4); // 192 KB

  kwpack_kernel<<<dim3(24, 8), dim3(64), 0, stream>>>(w_r, w_z, w_h, wpk);
  kproj_kernel<<<dim3(BL / 64), dim3(256), 0, stream>>>(x, wpk, k1k2, wsX, wsA);
  kscan_kernel<<<dim3(NB), dim3(512), 0, stream>>>(u_r, u_z, u_h, b_r, b_z, b_h,
                                                   cor, wsX, wsA, (float*)d_out);
}